// Round 19
// baseline (110.794 us; speedup 1.0000x reference)
//
#include <hip/hip_runtime.h>
#include <math.h>

#define B_ 8
#define N_ 128
#define M_ 256
#define F_ 256

#define LOG2E2 2.8853900817779268f  // 2*log2(e)

// ---------------------------------------------------------------------------
// K1-lite (r13, + counter zeroing): u[r][g] = (x[r,:].Uw[g,:] + Ub[g])*2log2e.
// Block 0 also zeroes the 8 per-batch ticket counters (kernel-boundary
// ordering makes them visible to k2kb; saves a memset node).
// ---------------------------------------------------------------------------
__global__ __launch_bounds__(256) void k1_lite(const float* __restrict__ x,
                                               const float* __restrict__ Uw,
                                               const float* __restrict__ Ub,
                                               float* __restrict__ u,
                                               unsigned* __restrict__ counter) {
  if (blockIdx.x == 0 && threadIdx.x < 8) counter[threadIdx.x] = 0u;

  const int g  = threadIdx.x;
  const int r0 = blockIdx.x * 4;
  const float* __restrict__ uwr = Uw + (size_t)g * F_;
  const float* __restrict__ xr  = x + (size_t)r0 * F_;

  float a0 = 0.f, a1 = 0.f, a2 = 0.f, a3 = 0.f;
#pragma unroll 4
  for (int f = 0; f < F_; f += 4) {
    const float4 wv = *(const float4*)&uwr[f];
    const float4 x0 = *(const float4*)&xr[0 * F_ + f];
    const float4 x1 = *(const float4*)&xr[1 * F_ + f];
    const float4 x2 = *(const float4*)&xr[2 * F_ + f];
    const float4 x3 = *(const float4*)&xr[3 * F_ + f];
    a0 = fmaf(wv.x, x0.x, a0); a0 = fmaf(wv.y, x0.y, a0);
    a0 = fmaf(wv.z, x0.z, a0); a0 = fmaf(wv.w, x0.w, a0);
    a1 = fmaf(wv.x, x1.x, a1); a1 = fmaf(wv.y, x1.y, a1);
    a1 = fmaf(wv.z, x1.z, a1); a1 = fmaf(wv.w, x1.w, a1);
    a2 = fmaf(wv.x, x2.x, a2); a2 = fmaf(wv.y, x2.y, a2);
    a2 = fmaf(wv.z, x2.z, a2); a2 = fmaf(wv.w, x2.w, a2);
    a3 = fmaf(wv.x, x3.x, a3); a3 = fmaf(wv.y, x3.y, a3);
    a3 = fmaf(wv.z, x3.z, a3); a3 = fmaf(wv.w, x3.w, a3);
  }
  const float ubv = Ub[g];
  u[(size_t)(r0 + 0) * F_ + g] = (a0 + ubv) * LOG2E2;
  u[(size_t)(r0 + 1) * F_ + g] = (a1 + ubv) * LOG2E2;
  u[(size_t)(r0 + 2) * F_ + g] = (a2 + ubv) * LOG2E2;
  u[(size_t)(r0 + 3) * F_ + g] = (a3 + ubv) * LOG2E2;
}

// ---------------------------------------------------------------------------
// K2KB: r18's proven k2 (paired-reciprocal hot loop, byte-identical) with the
// KB finish fused in via per-batch last-block tickets -> 2 launches total.
// Grid (mg 0..3, ns 0..15, b 0..7) = 512 blocks, 512 threads (8 waves).
// Batch b's 64 blocks each: write partials -> __threadfence (release) ->
// sync -> tid0 atomicAdd(counter[b]) (device-scope). Ticket 63 block
// acquires and runs phase B for batch b (softmaxes + pools). Phase B's
// register pressure (~25) is below the hot loop's peak, so regalloc of the
// hot path is unperturbed (the r10 spill came from pressure BEFORE the hot
// loop, not behind a cold branch).
// NO __launch_bounds__ (r8/r11/r16: pressure -> VGPR clamp -> spill).
// ---------------------------------------------------------------------------
__global__ void k2kb(const float* __restrict__ u,
                     const float* __restrict__ y,
                     const float* __restrict__ Ww,
                     const float* __restrict__ x,
                     float* __restrict__ rminp,
                     float* __restrict__ cminp,
                     unsigned* __restrict__ counter,
                     float* __restrict__ out) {
  __shared__ float us[8][F_];        //  8 KB
  __shared__ float red[8][8][64];    // 16 KB  [n][fc][m-lane]
  __shared__ float sm[8][64];        //  2 KB
  __shared__ float xw[N_];
  __shared__ float yw[M_];
  __shared__ float bred[8];
  __shared__ float part[2][256];
  __shared__ unsigned ticket_s;

  const int tid  = threadIdx.x;
  const int mg   = blockIdx.x;   // 0..3
  const int ns   = blockIdx.y;   // 0..15
  const int b    = blockIdx.z;   // 0..7
  const int n0   = ns * 8;
  const int m0   = mg * 64;
  const int lane = tid & 63;
  const int w    = tid >> 6;
  const int fc   = __builtin_amdgcn_readfirstlane(w);   // 0..7 (32 f each)

  // ---- stage this block's 8 u rows into LDS (coalesced, once) ----
  {
    const int r = tid >> 6, c = (tid & 63) * 4;
    *(float4*)&us[r][c] =
        *(const float4*)&u[(size_t)(b * N_ + n0 + r) * F_ + c];
  }

  // ---- per-thread y chunk (32 VGPR) + wave-uniform Ww chunk ----
  float4 yv[8];
  float4 wwv[8];
  {
    const float* yr = y + ((size_t)(b * M_ + m0 + lane)) * F_ + fc * 32;
    const float* wr = Ww + fc * 32;
#pragma unroll
    for (int j = 0; j < 8; ++j) {
      yv[j]  = *(const float4*)&yr[4 * j];
      wwv[j] = *(const float4*)&wr[4 * j];
    }
  }
  __syncthreads();

  // ---- hot loop: paired-reciprocal terms (EXACT math) ----
  //   w0/d0 + w1/d1 = (w0*d1 + w1*d0) * rcp(d0*d1),  d = 1 + 2^t
#define QUAD(nn, j, S0, S1)                                                   \
  do {                                                                        \
    const float4 uv = *(const float4*)&us[nn][fc * 32 + 4 * (j)];             \
    const float t0 = uv.x * yv[j].x;                                          \
    const float t1 = uv.y * yv[j].y;                                          \
    const float t2 = uv.z * yv[j].z;                                          \
    const float t3 = uv.w * yv[j].w;                                          \
    const float d0 = 1.f + __builtin_amdgcn_exp2f(t0);                        \
    const float d1 = 1.f + __builtin_amdgcn_exp2f(t1);                        \
    const float d2 = 1.f + __builtin_amdgcn_exp2f(t2);                        \
    const float d3 = 1.f + __builtin_amdgcn_exp2f(t3);                        \
    const float n01 = fmaf(wwv[j].x, d1, wwv[j].y * d0);                      \
    const float n23 = fmaf(wwv[j].z, d3, wwv[j].w * d2);                      \
    S0 = fmaf(n01, __builtin_amdgcn_rcpf(d0 * d1), S0);                       \
    S1 = fmaf(n23, __builtin_amdgcn_rcpf(d2 * d3), S1);                       \
  } while (0)

#define DO_N(nn, A)                                                                      \
  do {                                                                                   \
    float s0 = 0.f, s1 = 0.f;                                                            \
    QUAD(nn, 0, s0, s1); QUAD(nn, 1, s0, s1); QUAD(nn, 2, s0, s1); QUAD(nn, 3, s0, s1);  \
    QUAD(nn, 4, s0, s1); QUAD(nn, 5, s0, s1); QUAD(nn, 6, s0, s1); QUAD(nn, 7, s0, s1);  \
    A = s0 + s1;                                                                         \
  } while (0)

  float a0, a1, a2, a3, a4, a5, a6, a7;
  DO_N(0, a0); DO_N(1, a1); DO_N(2, a2); DO_N(3, a3);
  DO_N(4, a4); DO_N(5, a5); DO_N(6, a6); DO_N(7, a7);
#undef DO_N
#undef QUAD

  // ---- cross-fc sum ----
  red[0][fc][lane] = a0; red[1][fc][lane] = a1;
  red[2][fc][lane] = a2; red[3][fc][lane] = a3;
  red[4][fc][lane] = a4; red[5][fc][lane] = a5;
  red[6][fc][lane] = a6; red[7][fc][lane] = a7;
  __syncthreads();

  float S = 0.f;
#pragma unroll
  for (int k = 0; k < 8; ++k) S += red[w][k][lane];

  // row-min partial (over this block's 64 m)
  float r = S;
#pragma unroll
  for (int s = 32; s; s >>= 1) r = fminf(r, __shfl_xor(r, s));
  if (lane == 0) rminp[((size_t)b * 4 + mg) * N_ + n0 + w] = r;

  // col-min partial (over this block's 8 n)
  sm[w][lane] = S;
  __syncthreads();
  if (w == 0) {
    float c = sm[0][lane];
#pragma unroll
    for (int k = 1; k < 8; ++k) c = fminf(c, sm[k][lane]);
    cminp[((size_t)b * 16 + ns) * M_ + m0 + lane] = c;
  }

  // ---- per-batch last-block ticket ----
  __threadfence();                 // release this block's partials
  __syncthreads();
  if (tid == 0) ticket_s = atomicAdd(&counter[b], 1u);
  __syncthreads();
  if (ticket_s != 63u) return;
  __threadfence();                 // acquire all of batch b's partials

  // ---- Phase B for batch b (one block, 512 threads) ----
  // x attention: softmax over n of (-2 * min_m S)
  float rv = -INFINITY;
  if (tid < N_) {
    float v = INFINITY;
#pragma unroll
    for (int mg2 = 0; mg2 < 4; ++mg2)
      v = fminf(v, rminp[((size_t)b * 4 + mg2) * N_ + tid]);
    rv = -2.f * v;
  }
  float m1 = rv;
#pragma unroll
  for (int s = 32; s; s >>= 1) m1 = fmaxf(m1, __shfl_xor(m1, s));
  if (lane == 0) bred[w] = m1;
  __syncthreads();
  m1 = bred[0];
#pragma unroll
  for (int k = 1; k < 8; ++k) m1 = fmaxf(m1, bred[k]);
  __syncthreads();
  const float e1 = (tid < N_) ? __expf(rv - m1) : 0.f;
  float s1 = e1;
#pragma unroll
  for (int s = 32; s; s >>= 1) s1 += __shfl_xor(s1, s);
  if (lane == 0) bred[w] = s1;
  __syncthreads();
  s1 = bred[0] + bred[1] + bred[2] + bred[3] +
       bred[4] + bred[5] + bred[6] + bred[7];
  if (tid < N_) xw[tid] = e1 / s1;
  __syncthreads();

  // y attention: softmax over m of (-2 * min_n S)
  float cv = -INFINITY;
  if (tid < M_) {
    float c = INFINITY;
#pragma unroll
    for (int k = 0; k < 16; ++k)
      c = fminf(c, cminp[((size_t)b * 16 + k) * M_ + tid]);
    cv = -2.f * c;
  }
  float m2 = cv;
#pragma unroll
  for (int s = 32; s; s >>= 1) m2 = fmaxf(m2, __shfl_xor(m2, s));
  if (lane == 0) bred[w] = m2;
  __syncthreads();
  m2 = bred[0];
#pragma unroll
  for (int k = 1; k < 8; ++k) m2 = fmaxf(m2, bred[k]);
  __syncthreads();
  const float e2 = (tid < M_) ? __expf(cv - m2) : 0.f;
  float s2 = e2;
#pragma unroll
  for (int s = 32; s; s >>= 1) s2 += __shfl_xor(s2, s);
  if (lane == 0) bred[w] = s2;
  __syncthreads();
  s2 = bred[0] + bred[1] + bred[2] + bred[3] +
       bred[4] + bred[5] + bred[6] + bred[7];
  if (tid < M_) yw[tid] = e2 / s2;
  __syncthreads();

  // pooled outputs, 2-way split over the sum dimension
  const int q = tid >> 8;   // 0..1
  const int f = tid & 255;
  float accx = 0.f;
#pragma unroll 4
  for (int n = q; n < N_; n += 2)
    accx = fmaf(xw[n], x[(size_t)(b * N_ + n) * F_ + f], accx);
  part[q][f] = accx;
  __syncthreads();
  if (tid < 256) out[b * (2 * F_) + f] = part[0][f] + part[1][f];
  __syncthreads();
  float accy = 0.f;
#pragma unroll 4
  for (int mm = q; mm < M_; mm += 2)
    accy = fmaf(yw[mm], y[(size_t)(b * M_ + mm) * F_ + f], accy);
  part[q][f] = accy;
  __syncthreads();
  if (tid < 256) out[b * (2 * F_) + F_ + f] = part[0][f] + part[1][f];
}

// ---------------------------------------------------------------------------
extern "C" void kernel_launch(void* const* d_in, const int* in_sizes, int n_in,
                              void* d_out, int out_size, void* d_ws, size_t ws_size,
                              hipStream_t stream) {
  (void)in_sizes; (void)n_in; (void)out_size; (void)ws_size;
  const float* x  = (const float*)d_in[0];
  const float* y  = (const float*)d_in[1];
  const float* Uw = (const float*)d_in[2];
  const float* Ub = (const float*)d_in[3];
  const float* Ww = (const float*)d_in[4];
  // d_in[5] (W_b) unused: max/softmax pipeline is shift-invariant.

  float* u        = (float*)d_ws;                 // [B][N][F]    262144 f
  float* rminp    = u + B_ * N_ * F_;             // [B][4][N]      4096 f
  float* cminp    = rminp + B_ * 4 * N_;          // [B][16][M]   32768 f
  unsigned* cnt   = (unsigned*)(cminp + B_ * 16 * M_);  // 8 u32
  float* outp     = (float*)d_out;

  k1_lite<<<dim3((B_ * N_) / 4), 256, 0, stream>>>(x, Uw, Ub, u, cnt);
  k2kb<<<dim3(4, 16, B_), 512, 0, stream>>>(u, y, Ww, x, rminp, cminp, cnt,
                                            outp);
}

// Round 20
// 39.836 us; speedup vs baseline: 2.7813x; 2.7813x over previous
//
#include <hip/hip_runtime.h>
#include <math.h>

#define B_ 8
#define N_ 128
#define M_ 256
#define F_ 256

// ---------------------------------------------------------------------------
// K1-lite (r13, scale removed): u[r][g] = x[r,:].Uw[g,:] + Ub[g]   (plain).
// ---------------------------------------------------------------------------
__global__ __launch_bounds__(256) void k1_lite(const float* __restrict__ x,
                                               const float* __restrict__ Uw,
                                               const float* __restrict__ Ub,
                                               float* __restrict__ u) {
  const int g  = threadIdx.x;
  const int r0 = blockIdx.x * 4;
  const float* __restrict__ uwr = Uw + (size_t)g * F_;
  const float* __restrict__ xr  = x + (size_t)r0 * F_;

  float a0 = 0.f, a1 = 0.f, a2 = 0.f, a3 = 0.f;
#pragma unroll 4
  for (int f = 0; f < F_; f += 4) {
    const float4 wv = *(const float4*)&uwr[f];
    const float4 x0 = *(const float4*)&xr[0 * F_ + f];
    const float4 x1 = *(const float4*)&xr[1 * F_ + f];
    const float4 x2 = *(const float4*)&xr[2 * F_ + f];
    const float4 x3 = *(const float4*)&xr[3 * F_ + f];
    a0 = fmaf(wv.x, x0.x, a0); a0 = fmaf(wv.y, x0.y, a0);
    a0 = fmaf(wv.z, x0.z, a0); a0 = fmaf(wv.w, x0.w, a0);
    a1 = fmaf(wv.x, x1.x, a1); a1 = fmaf(wv.y, x1.y, a1);
    a1 = fmaf(wv.z, x1.z, a1); a1 = fmaf(wv.w, x1.w, a1);
    a2 = fmaf(wv.x, x2.x, a2); a2 = fmaf(wv.y, x2.y, a2);
    a2 = fmaf(wv.z, x2.z, a2); a2 = fmaf(wv.w, x2.w, a2);
    a3 = fmaf(wv.x, x3.x, a3); a3 = fmaf(wv.y, x3.y, a3);
    a3 = fmaf(wv.z, x3.z, a3); a3 = fmaf(wv.w, x3.w, a3);
  }
  const float ubv = Ub[g];
  u[(size_t)(r0 + 0) * F_ + g] = a0 + ubv;
  u[(size_t)(r0 + 1) * F_ + g] = a1 + ubv;
  u[(size_t)(r0 + 2) * F_ + g] = a2 + ubv;
  u[(size_t)(r0 + 3) * F_ + g] = a3 + ubv;
}

// ---------------------------------------------------------------------------
// K2 v13: r13/r18 geometry (proven spill-free), hot loop = EXP-FREE rational
// tanh. Hypothesis from r13-r18: v_exp_f32 is the slow pipe (exp count was
// the one invariant across all flat variants). Padé(7,6) with |x| clamped to
// 5: tanh(x) ~ x*n(q)/d(q), q=x^2; abs err <= ~1e-4 (hand-verified at
// x=1,2,3,4,5; clamp bound 9.2e-5). Paired reciprocal (exact):
//   p0/d0 + p1/d1 = (p0*d1 + p1*d0)*rcp(d0*d1)
// Per term: ~14 VALU + 0.25 trans (rcp 128/thread; exp2 count = ZERO).
// alpha[n][m] = sum_f Ww[f]*tanh(u[n][f]*y[m][f])  (W_b dropped: softmax
// shift-invariant). MAX-reduce alpha directly.
// Grid (mg 0..3, ns 0..15, b 0..7) = 512 blocks, 512 threads (8 waves).
// NO __launch_bounds__ (r8/r11/r16/r19: pressure -> VGPR clamp -> spill).
// Partials: rmaxp[b][mg][n] (max over 64 m), cmaxp[b][ns][m] (max over 8 n).
// ---------------------------------------------------------------------------
__global__ void k2_alpha(const float* __restrict__ u,
                         const float* __restrict__ y,
                         const float* __restrict__ Ww,
                         float* __restrict__ rmaxp,
                         float* __restrict__ cmaxp) {
  __shared__ float us[8][F_];        //  8 KB
  __shared__ float red[8][8][64];    // 16 KB  [n][fc][m-lane]
  __shared__ float sm[8][64];        //  2 KB

  const int tid  = threadIdx.x;
  const int mg   = blockIdx.x;   // 0..3
  const int ns   = blockIdx.y;   // 0..15
  const int b    = blockIdx.z;   // 0..7
  const int n0   = ns * 8;
  const int m0   = mg * 64;
  const int lane = tid & 63;
  const int w    = tid >> 6;
  const int fc   = __builtin_amdgcn_readfirstlane(w);   // 0..7 (32 f each)

  // ---- stage this block's 8 u rows into LDS (coalesced, once) ----
  {
    const int r = tid >> 6, c = (tid & 63) * 4;
    *(float4*)&us[r][c] =
        *(const float4*)&u[(size_t)(b * N_ + n0 + r) * F_ + c];
  }

  // ---- per-thread y chunk (32 VGPR) + wave-uniform Ww chunk ----
  float4 yv[8];
  float4 wwv[8];
  {
    const float* yr = y + ((size_t)(b * M_ + m0 + lane)) * F_ + fc * 32;
    const float* wr = Ww + fc * 32;
#pragma unroll
    for (int j = 0; j < 8; ++j) {
      yv[j]  = *(const float4*)&yr[4 * j];
      wwv[j] = *(const float4*)&wr[4 * j];
    }
  }
  __syncthreads();

  // ---- hot loop: rational tanh, paired rcp ----
  // PAIR: two terms -> one v_rcp. All else VALU.
#define PAIR(UA, YA, WA, UB2, YB, WB, SS)                                     \
  do {                                                                        \
    const float x0 = (UA) * (YA);                                             \
    const float x1 = (UB2) * (YB);                                            \
    const float c0 = fminf(fmaxf(x0, -5.f), 5.f);                             \
    const float c1 = fminf(fmaxf(x1, -5.f), 5.f);                             \
    const float q0 = c0 * c0;                                                 \
    const float q1 = c1 * c1;                                                 \
    const float nn0 = fmaf(q0, fmaf(q0, fmaf(q0, 7.3999e-6f, 2.79721e-3f),    \
                                    0.1282051f), 1.f);                        \
    const float dd0 = fmaf(q0, fmaf(q0, fmaf(q0, 2.07183e-4f, 0.02331002f),   \
                                    0.4615385f), 1.f);                        \
    const float nn1 = fmaf(q1, fmaf(q1, fmaf(q1, 7.3999e-6f, 2.79721e-3f),    \
                                    0.1282051f), 1.f);                        \
    const float dd1 = fmaf(q1, fmaf(q1, fmaf(q1, 2.07183e-4f, 0.02331002f),   \
                                    0.4615385f), 1.f);                        \
    const float p0 = ((WA) * c0) * nn0;                                       \
    const float p1 = ((WB) * c1) * nn1;                                       \
    const float nmr = fmaf(p0, dd1, p1 * dd0);                                \
    SS = fmaf(nmr, __builtin_amdgcn_rcpf(dd0 * dd1), SS);                     \
  } while (0)

#define QUAD(nn, j, S0, S1)                                                   \
  do {                                                                        \
    const float4 uv = *(const float4*)&us[nn][fc * 32 + 4 * (j)];             \
    PAIR(uv.x, yv[j].x, wwv[j].x, uv.y, yv[j].y, wwv[j].y, S0);               \
    PAIR(uv.z, yv[j].z, wwv[j].z, uv.w, yv[j].w, wwv[j].w, S1);               \
  } while (0)

#define DO_N(nn, A)                                                                      \
  do {                                                                                   \
    float s0 = 0.f, s1 = 0.f;                                                            \
    QUAD(nn, 0, s0, s1); QUAD(nn, 1, s0, s1); QUAD(nn, 2, s0, s1); QUAD(nn, 3, s0, s1);  \
    QUAD(nn, 4, s0, s1); QUAD(nn, 5, s0, s1); QUAD(nn, 6, s0, s1); QUAD(nn, 7, s0, s1);  \
    A = s0 + s1;                                                                         \
  } while (0)

  float a0, a1, a2, a3, a4, a5, a6, a7;
  DO_N(0, a0); DO_N(1, a1); DO_N(2, a2); DO_N(3, a3);
  DO_N(4, a4); DO_N(5, a5); DO_N(6, a6); DO_N(7, a7);
#undef DO_N
#undef QUAD
#undef PAIR

  // ---- cross-fc sum ----
  red[0][fc][lane] = a0; red[1][fc][lane] = a1;
  red[2][fc][lane] = a2; red[3][fc][lane] = a3;
  red[4][fc][lane] = a4; red[5][fc][lane] = a5;
  red[6][fc][lane] = a6; red[7][fc][lane] = a7;
  __syncthreads();

  // wave w finalizes n = w over its 64 m-lanes: S = alpha[n0+w][m0+lane]
  float S = 0.f;
#pragma unroll
  for (int k = 0; k < 8; ++k) S += red[w][k][lane];

  // row-MAX partial (over this block's 64 m)
  float r = S;
#pragma unroll
  for (int s = 32; s; s >>= 1) r = fmaxf(r, __shfl_xor(r, s));
  if (lane == 0) rmaxp[((size_t)b * 4 + mg) * N_ + n0 + w] = r;

  // col-MAX partial (over this block's 8 n)
  sm[w][lane] = S;
  __syncthreads();
  if (w == 0) {
    float c = sm[0][lane];
#pragma unroll
    for (int k = 1; k < 8; ++k) c = fmaxf(c, sm[k][lane]);
    cmaxp[((size_t)b * 16 + ns) * M_ + m0 + lane] = c;
  }
}

// ---------------------------------------------------------------------------
// KB: 64 blocks (b x task x f-quarter), 256 threads. Softmax on the maxes
// directly (alpha-space now, no -2 transform).
// ---------------------------------------------------------------------------
__global__ __launch_bounds__(256) void kb_final(
    const float* __restrict__ x, const float* __restrict__ y,
    const float* __restrict__ rmaxp, const float* __restrict__ cmaxp,
    float* __restrict__ out) {
  const int b    = blockIdx.x;
  const int task = blockIdx.y;
  const int fq   = blockIdx.z;
  const int tid  = threadIdx.x;
  const int w    = tid >> 6;
  __shared__ float wgt[M_];
  __shared__ float redv[4];
  __shared__ float part[4][64];

  if (task == 0) {
    float rv = -INFINITY;
    if (tid < N_) {
#pragma unroll
      for (int mg = 0; mg < 4; ++mg)
        rv = fmaxf(rv, rmaxp[((size_t)b * 4 + mg) * N_ + tid]);
    }
    float m1 = rv;
#pragma unroll
    for (int s = 32; s; s >>= 1) m1 = fmaxf(m1, __shfl_xor(m1, s));
    if ((tid & 63) == 0) redv[w] = m1;
    __syncthreads();
    m1 = fmaxf(fmaxf(redv[0], redv[1]), fmaxf(redv[2], redv[3]));
    __syncthreads();
    const float e1 = (tid < N_) ? __expf(rv - m1) : 0.f;
    float s1 = e1;
#pragma unroll
    for (int s = 32; s; s >>= 1) s1 += __shfl_xor(s1, s);
    if ((tid & 63) == 0) redv[w] = s1;
    __syncthreads();
    s1 = redv[0] + redv[1] + redv[2] + redv[3];
    if (tid < N_) wgt[tid] = e1 / s1;
    __syncthreads();

    const int f = fq * 64 + (tid & 63);
    float acc = 0.f;
#pragma unroll 8
    for (int n = w; n < N_; n += 4)
      acc = fmaf(wgt[n], x[(size_t)(b * N_ + n) * F_ + f], acc);
    part[w][tid & 63] = acc;
    __syncthreads();
    if (tid < 64)
      out[b * (2 * F_) + fq * 64 + tid] =
          part[0][tid] + part[1][tid] + part[2][tid] + part[3][tid];
  } else {
    float cv = -INFINITY;
    {
#pragma unroll
      for (int ns = 0; ns < 16; ++ns)
        cv = fmaxf(cv, cmaxp[((size_t)b * 16 + ns) * M_ + tid]);
    }
    float m2 = cv;
#pragma unroll
    for (int s = 32; s; s >>= 1) m2 = fmaxf(m2, __shfl_xor(m2, s));
    if ((tid & 63) == 0) redv[w] = m2;
    __syncthreads();
    m2 = fmaxf(fmaxf(redv[0], redv[1]), fmaxf(redv[2], redv[3]));
    __syncthreads();
    const float e2 = __expf(cv - m2);
    float s2 = e2;
#pragma unroll
    for (int s = 32; s; s >>= 1) s2 += __shfl_xor(s2, s);
    if ((tid & 63) == 0) redv[w] = s2;
    __syncthreads();
    s2 = redv[0] + redv[1] + redv[2] + redv[3];
    wgt[tid] = e2 / s2;
    __syncthreads();

    const int f = fq * 64 + (tid & 63);
    float acc = 0.f;
#pragma unroll 8
    for (int m = w; m < M_; m += 4)
      acc = fmaf(wgt[m], y[(size_t)(b * M_ + m) * F_ + f], acc);
    part[w][tid & 63] = acc;
    __syncthreads();
    if (tid < 64)
      out[b * (2 * F_) + F_ + fq * 64 + tid] =
          part[0][tid] + part[1][tid] + part[2][tid] + part[3][tid];
  }
}

// ---------------------------------------------------------------------------
extern "C" void kernel_launch(void* const* d_in, const int* in_sizes, int n_in,
                              void* d_out, int out_size, void* d_ws, size_t ws_size,
                              hipStream_t stream) {
  (void)in_sizes; (void)n_in; (void)out_size; (void)ws_size;
  const float* x  = (const float*)d_in[0];
  const float* y  = (const float*)d_in[1];
  const float* Uw = (const float*)d_in[2];
  const float* Ub = (const float*)d_in[3];
  const float* Ww = (const float*)d_in[4];
  // d_in[5] (W_b) unused: max/softmax pipeline is shift-invariant.

  float* u     = (float*)d_ws;                 // [B][N][F]    262144 f
  float* rmaxp = u + B_ * N_ * F_;             // [B][4][N]      4096 f
  float* cmaxp = rmaxp + B_ * 4 * N_;          // [B][16][M]   32768 f
  float* outp  = (float*)d_out;

  k1_lite<<<dim3((B_ * N_) / 4), 256, 0, stream>>>(x, Uw, Ub, u);
  k2_alpha<<<dim3(4, 16, B_), 512, 0, stream>>>(u, y, Ww, rmaxp, cmaxp);
  kb_final<<<dim3(B_, 2, 4), 256, 0, stream>>>(x, y, rmaxp, cmaxp, outp);
}

// Round 21
// 35.350 us; speedup vs baseline: 3.1342x; 1.1269x over previous
//
#include <hip/hip_runtime.h>
#include <math.h>

#define B_ 8
#define N_ 128
#define M_ 256
#define F_ 256

#define LOG2E2 2.8853900817779268f  // 2*log2(e)

// ---------------------------------------------------------------------------
// K1-lite (r13, unchanged): u[r][g] = (x[r,:].Uw[g,:] + Ub[g]) * 2log2e.
// ---------------------------------------------------------------------------
__global__ __launch_bounds__(256) void k1_lite(const float* __restrict__ x,
                                               const float* __restrict__ Uw,
                                               const float* __restrict__ Ub,
                                               float* __restrict__ u) {
  const int g  = threadIdx.x;
  const int r0 = blockIdx.x * 4;
  const float* __restrict__ uwr = Uw + (size_t)g * F_;
  const float* __restrict__ xr  = x + (size_t)r0 * F_;

  float a0 = 0.f, a1 = 0.f, a2 = 0.f, a3 = 0.f;
#pragma unroll 4
  for (int f = 0; f < F_; f += 4) {
    const float4 wv = *(const float4*)&uwr[f];
    const float4 x0 = *(const float4*)&xr[0 * F_ + f];
    const float4 x1 = *(const float4*)&xr[1 * F_ + f];
    const float4 x2 = *(const float4*)&xr[2 * F_ + f];
    const float4 x3 = *(const float4*)&xr[3 * F_ + f];
    a0 = fmaf(wv.x, x0.x, a0); a0 = fmaf(wv.y, x0.y, a0);
    a0 = fmaf(wv.z, x0.z, a0); a0 = fmaf(wv.w, x0.w, a0);
    a1 = fmaf(wv.x, x1.x, a1); a1 = fmaf(wv.y, x1.y, a1);
    a1 = fmaf(wv.z, x1.z, a1); a1 = fmaf(wv.w, x1.w, a1);
    a2 = fmaf(wv.x, x2.x, a2); a2 = fmaf(wv.y, x2.y, a2);
    a2 = fmaf(wv.z, x2.z, a2); a2 = fmaf(wv.w, x2.w, a2);
    a3 = fmaf(wv.x, x3.x, a3); a3 = fmaf(wv.y, x3.y, a3);
    a3 = fmaf(wv.z, x3.z, a3); a3 = fmaf(wv.w, x3.w, a3);
  }
  const float ubv = Ub[g];
  u[(size_t)(r0 + 0) * F_ + g] = (a0 + ubv) * LOG2E2;
  u[(size_t)(r0 + 1) * F_ + g] = (a1 + ubv) * LOG2E2;
  u[(size_t)(r0 + 2) * F_ + g] = (a2 + ubv) * LOG2E2;
  u[(size_t)(r0 + 3) * F_ + g] = (a3 + ubv) * LOG2E2;
}

// ---------------------------------------------------------------------------
// K2 v14 = r18's kernel with __launch_bounds__(512, 1).
// r20 profile showed VGPR_Count=32 (SGPR=64): wwv lives in SGPRs, but
// yv[8] (32 VGPR) cannot be register-resident at a 32-VGPR allocation ->
// the compiler re-issues the y loads per use (8x refetch of 64 float4 per
// thread). THAT is the invariant ~26 us, not the trans pipe. (512,1) = min
// 1 wave/EU = the least-constrained VGPR budget (256), the one setting
// never tried: (512,2)->52, (512,4)->32, bare (512)->32, none->32..64.
// Hot loop math: paired reciprocal (EXACT):
//   w0/d0 + w1/d1 = (w0*d1 + w1*d0) * rcp(d0*d1),  d = 1 + 2^t
// S[n][m] = sum_f Ww[f]/(1+2^(us[n][f]*y[m][f])); alpha = Wsum - 2S
// monotone-decreasing => MIN-reduce S (Wsum, W_b cancel in max/softmax).
// Grid (mg 0..3, ns 0..15, b 0..7) = 512 blocks, 512 threads (8 waves).
// Partials: rminp[b][mg][n] (min over 64 m), cminp[b][ns][m] (min over 8 n).
// ---------------------------------------------------------------------------
__global__ __launch_bounds__(512, 1) void k2_alpha(
    const float* __restrict__ u, const float* __restrict__ y,
    const float* __restrict__ Ww,
    float* __restrict__ rminp, float* __restrict__ cminp) {
  __shared__ float us[8][F_];        //  8 KB
  __shared__ float red[8][8][64];    // 16 KB  [n][fc][m-lane]
  __shared__ float sm[8][64];        //  2 KB

  const int tid  = threadIdx.x;
  const int mg   = blockIdx.x;   // 0..3
  const int ns   = blockIdx.y;   // 0..15
  const int b    = blockIdx.z;   // 0..7
  const int n0   = ns * 8;
  const int m0   = mg * 64;
  const int lane = tid & 63;
  const int w    = tid >> 6;
  const int fc   = __builtin_amdgcn_readfirstlane(w);   // 0..7 (32 f each)

  // ---- stage this block's 8 u rows into LDS (coalesced, once) ----
  {
    const int r = tid >> 6, c = (tid & 63) * 4;
    *(float4*)&us[r][c] =
        *(const float4*)&u[(size_t)(b * N_ + n0 + r) * F_ + c];
  }

  // ---- per-thread y chunk (32 VGPR) + wave-uniform Ww chunk (SGPRs) ----
  float4 yv[8];
  float4 wwv[8];
  {
    const float* yr = y + ((size_t)(b * M_ + m0 + lane)) * F_ + fc * 32;
    const float* wr = Ww + fc * 32;
#pragma unroll
    for (int j = 0; j < 8; ++j) {
      yv[j]  = *(const float4*)&yr[4 * j];
      wwv[j] = *(const float4*)&wr[4 * j];
    }
  }
  __syncthreads();

  // ---- hot loop: paired-reciprocal terms (EXACT math) ----
#define QUAD(nn, j, S0, S1)                                                   \
  do {                                                                        \
    const float4 uv = *(const float4*)&us[nn][fc * 32 + 4 * (j)];             \
    const float t0 = uv.x * yv[j].x;                                          \
    const float t1 = uv.y * yv[j].y;                                          \
    const float t2 = uv.z * yv[j].z;                                          \
    const float t3 = uv.w * yv[j].w;                                          \
    const float d0 = 1.f + __builtin_amdgcn_exp2f(t0);                        \
    const float d1 = 1.f + __builtin_amdgcn_exp2f(t1);                        \
    const float d2 = 1.f + __builtin_amdgcn_exp2f(t2);                        \
    const float d3 = 1.f + __builtin_amdgcn_exp2f(t3);                        \
    const float n01 = fmaf(wwv[j].x, d1, wwv[j].y * d0);                      \
    const float n23 = fmaf(wwv[j].z, d3, wwv[j].w * d2);                      \
    S0 = fmaf(n01, __builtin_amdgcn_rcpf(d0 * d1), S0);                       \
    S1 = fmaf(n23, __builtin_amdgcn_rcpf(d2 * d3), S1);                       \
  } while (0)

#define DO_N(nn, A)                                                                      \
  do {                                                                                   \
    float s0 = 0.f, s1 = 0.f;                                                            \
    QUAD(nn, 0, s0, s1); QUAD(nn, 1, s0, s1); QUAD(nn, 2, s0, s1); QUAD(nn, 3, s0, s1);  \
    QUAD(nn, 4, s0, s1); QUAD(nn, 5, s0, s1); QUAD(nn, 6, s0, s1); QUAD(nn, 7, s0, s1);  \
    A = s0 + s1;                                                                         \
  } while (0)

  float a0, a1, a2, a3, a4, a5, a6, a7;
  DO_N(0, a0); DO_N(1, a1); DO_N(2, a2); DO_N(3, a3);
  DO_N(4, a4); DO_N(5, a5); DO_N(6, a6); DO_N(7, a7);
#undef DO_N
#undef QUAD

  // ---- cross-fc sum ----
  red[0][fc][lane] = a0; red[1][fc][lane] = a1;
  red[2][fc][lane] = a2; red[3][fc][lane] = a3;
  red[4][fc][lane] = a4; red[5][fc][lane] = a5;
  red[6][fc][lane] = a6; red[7][fc][lane] = a7;
  __syncthreads();

  float S = 0.f;
#pragma unroll
  for (int k = 0; k < 8; ++k) S += red[w][k][lane];

  // row-min partial (over this block's 64 m)
  float r = S;
#pragma unroll
  for (int s = 32; s; s >>= 1) r = fminf(r, __shfl_xor(r, s));
  if (lane == 0) rminp[((size_t)b * 4 + mg) * N_ + n0 + w] = r;

  // col-min partial (over this block's 8 n)
  sm[w][lane] = S;
  __syncthreads();
  if (w == 0) {
    float c = sm[0][lane];
#pragma unroll
    for (int k = 1; k < 8; ++k) c = fminf(c, sm[k][lane]);
    cminp[((size_t)b * 16 + ns) * M_ + m0 + lane] = c;
  }
}

// ---------------------------------------------------------------------------
// KB (r14/r18, unchanged): 64 blocks (b x task x f-quarter), 256 threads.
// Softmax inputs are -2 * min-partials (exact, shift-invariant).
// ---------------------------------------------------------------------------
__global__ __launch_bounds__(256) void kb_final(
    const float* __restrict__ x, const float* __restrict__ y,
    const float* __restrict__ rminp, const float* __restrict__ cminp,
    float* __restrict__ out) {
  const int b    = blockIdx.x;
  const int task = blockIdx.y;
  const int fq   = blockIdx.z;
  const int tid  = threadIdx.x;
  const int w    = tid >> 6;
  __shared__ float wgt[M_];
  __shared__ float redv[4];
  __shared__ float part[4][64];

  if (task == 0) {
    float rv = -INFINITY;
    if (tid < N_) {
      float v = INFINITY;
#pragma unroll
      for (int mg = 0; mg < 4; ++mg)
        v = fminf(v, rminp[((size_t)b * 4 + mg) * N_ + tid]);
      rv = -2.f * v;
    }
    float m1 = rv;
#pragma unroll
    for (int s = 32; s; s >>= 1) m1 = fmaxf(m1, __shfl_xor(m1, s));
    if ((tid & 63) == 0) redv[w] = m1;
    __syncthreads();
    m1 = fmaxf(fmaxf(redv[0], redv[1]), fmaxf(redv[2], redv[3]));
    __syncthreads();
    const float e1 = (tid < N_) ? __expf(rv - m1) : 0.f;
    float s1 = e1;
#pragma unroll
    for (int s = 32; s; s >>= 1) s1 += __shfl_xor(s1, s);
    if ((tid & 63) == 0) redv[w] = s1;
    __syncthreads();
    s1 = redv[0] + redv[1] + redv[2] + redv[3];
    if (tid < N_) wgt[tid] = e1 / s1;
    __syncthreads();

    const int f = fq * 64 + (tid & 63);
    float acc = 0.f;
#pragma unroll 8
    for (int n = w; n < N_; n += 4)
      acc = fmaf(wgt[n], x[(size_t)(b * N_ + n) * F_ + f], acc);
    part[w][tid & 63] = acc;
    __syncthreads();
    if (tid < 64)
      out[b * (2 * F_) + fq * 64 + tid] =
          part[0][tid] + part[1][tid] + part[2][tid] + part[3][tid];
  } else {
    float cv;
    {
      float c = INFINITY;
#pragma unroll
      for (int ns = 0; ns < 16; ++ns)
        c = fminf(c, cminp[((size_t)b * 16 + ns) * M_ + tid]);
      cv = -2.f * c;
    }
    float m2 = cv;
#pragma unroll
    for (int s = 32; s; s >>= 1) m2 = fmaxf(m2, __shfl_xor(m2, s));
    if ((tid & 63) == 0) redv[w] = m2;
    __syncthreads();
    m2 = fmaxf(fmaxf(redv[0], redv[1]), fmaxf(redv[2], redv[3]));
    __syncthreads();
    const float e2 = __expf(cv - m2);
    float s2 = e2;
#pragma unroll
    for (int s = 32; s; s >>= 1) s2 += __shfl_xor(s2, s);
    if ((tid & 63) == 0) redv[w] = s2;
    __syncthreads();
    s2 = redv[0] + redv[1] + redv[2] + redv[3];
    wgt[tid] = e2 / s2;
    __syncthreads();

    const int f = fq * 64 + (tid & 63);
    float acc = 0.f;
#pragma unroll 8
    for (int m = w; m < M_; m += 4)
      acc = fmaf(wgt[m], y[(size_t)(b * M_ + m) * F_ + f], acc);
    part[w][tid & 63] = acc;
    __syncthreads();
    if (tid < 64)
      out[b * (2 * F_) + F_ + fq * 64 + tid] =
          part[0][tid] + part[1][tid] + part[2][tid] + part[3][tid];
  }
}

// ---------------------------------------------------------------------------
extern "C" void kernel_launch(void* const* d_in, const int* in_sizes, int n_in,
                              void* d_out, int out_size, void* d_ws, size_t ws_size,
                              hipStream_t stream) {
  (void)in_sizes; (void)n_in; (void)out_size; (void)ws_size;
  const float* x  = (const float*)d_in[0];
  const float* y  = (const float*)d_in[1];
  const float* Uw = (const float*)d_in[2];
  const float* Ub = (const float*)d_in[3];
  const float* Ww = (const float*)d_in[4];
  // d_in[5] (W_b) unused: max/softmax pipeline is shift-invariant.

  float* u     = (float*)d_ws;                 // [B][N][F]    262144 f
  float* rminp = u + B_ * N_ * F_;             // [B][4][N]      4096 f
  float* cminp = rminp + B_ * 4 * N_;          // [B][16][M]   32768 f
  float* outp  = (float*)d_out;

  k1_lite<<<dim3((B_ * N_) / 4), 256, 0, stream>>>(x, Uw, Ub, u);
  k2_alpha<<<dim3(4, 16, B_), 512, 0, stream>>>(u, y, Ww, rminp, cminp);
  kb_final<<<dim3(B_, 2, 4), 256, 0, stream>>>(x, y, rminp, cminp, outp);
}